// Round 1
// baseline (4875.335 us; speedup 1.0000x reference)
//
#include <hip/hip_runtime.h>
#include <hip/hip_bf16.h>

#define NN 50000
#define NE 800000
#define HD 128
#define NB 512

constexpr float BNS = 0.9999950000374998f;  // 1/sqrt(1+1e-5)

// ---------------- counts ----------------
__global__ void k_count(const int* __restrict__ batch, float* __restrict__ counts) {
    int i = blockIdx.x * 256 + threadIdx.x;
    if (i < NN) atomicAdd(&counts[batch[i]], 1.0f);
}

// ---------------- vn init ----------------
__global__ void k_vn_init(const float* __restrict__ vn_emb, float* __restrict__ vn) {
    int idx = blockIdx.x * 256 + threadIdx.x;  // < NB*HD
    vn[idx] = vn_emb[idx & 127];
}

// ---------------- h += vn[batch] ----------------
__global__ void k_addvn(float* __restrict__ h, const float* __restrict__ vn,
                        const int* __restrict__ batch) {
    int idx = blockIdx.x * 256 + threadIdx.x;  // < NN*32
    int i = idx >> 5, q = idx & 31;
    float4 v = ((float4*)h)[idx];
    float4 u = ((const float4*)vn)[batch[i] * 32 + q];
    v.x += u.x; v.y += u.y; v.z += u.z; v.w += u.w;
    ((float4*)h)[idx] = v;
}

// ---------------- edge scatter: agg[dst] += h[src] ----------------
__global__ void k_scatter(const int* __restrict__ ei, const float* __restrict__ h,
                          float* __restrict__ agg) {
    int idx = blockIdx.x * 256 + threadIdx.x;  // < NE*32
    int e = idx >> 5, q = idx & 31;
    int s = ei[e];
    int d = ei[NE + e];
    float4 v = ((const float4*)h)[s * 32 + q];
    float* p = agg + d * 128 + q * 4;
    atomicAdd(p + 0, v.x);
    atomicAdd(p + 1, v.y);
    atomicAdd(p + 2, v.z);
    atomicAdd(p + 3, v.w);
}

// ---------------- pool: acc[batch[i]] += h[i] ----------------
__global__ void k_pool(const float* __restrict__ h, const int* __restrict__ batch,
                       float* __restrict__ acc) {
    int idx = blockIdx.x * 256 + threadIdx.x;  // < NN*32
    int i = idx >> 5, q = idx & 31;
    float4 v = ((const float4*)h)[idx];
    int b = batch[i];
    float* p = acc + b * 128 + q * 4;
    atomicAdd(p + 0, v.x);
    atomicAdd(p + 1, v.y);
    atomicAdd(p + 2, v.z);
    atomicAdd(p + 3, v.w);
}

// ---------------- GEMM: out = epi((A [+A2]) @ W + bias) ----------------
// A [nrows,128] row-major, W [128,128] row-major (k,out), out [nrows,128]
// EPI: 0 = none, 1 = leaky, 2 = bn(leaky(x))
template <int EPI, bool ADD2>
__global__ __launch_bounds__(256) void k_gemm128(
    const float* __restrict__ A, const float* __restrict__ A2,
    const float* __restrict__ W, const float* __restrict__ bias,
    const float* __restrict__ gg, const float* __restrict__ bb,
    float* __restrict__ out, int nrows) {
    __shared__ float sW[128 * 128];
    const int t = threadIdx.x;
    {
        const float4* W4 = (const float4*)W;
        float4* sW4 = (float4*)sW;
#pragma unroll
        for (int i = 0; i < 16; ++i) sW4[t + 256 * i] = W4[t + 256 * i];
    }
    __syncthreads();

    const int cg = t & 15;   // column group: cols = cg*2 + j1 + 32*j2
    const int rq = t >> 4;   // row quad 0..15
    const int row0 = blockIdx.x * 64 + rq * 4;

    float acc[4][8];
#pragma unroll
    for (int i = 0; i < 4; ++i)
#pragma unroll
        for (int j = 0; j < 8; ++j) acc[i][j] = 0.f;

    const float4* A4 = (const float4*)A;
    const float4* B4 = (const float4*)A2;

    int rl[4];
#pragma unroll
    for (int i = 0; i < 4; ++i) rl[i] = min(row0 + i, nrows - 1);

    for (int k4 = 0; k4 < 32; ++k4) {
        float4 av[4];
#pragma unroll
        for (int i = 0; i < 4; ++i) {
            float4 v = A4[rl[i] * 32 + k4];
            if (ADD2) {
                float4 u = B4[rl[i] * 32 + k4];
                v.x += u.x; v.y += u.y; v.z += u.z; v.w += u.w;
            }
            av[i] = v;
        }
#pragma unroll
        for (int kk = 0; kk < 4; ++kk) {
            const int k = k4 * 4 + kk;
            float w[8];
#pragma unroll
            for (int j2 = 0; j2 < 4; ++j2) {
                float2 wv = *(const float2*)&sW[k * 128 + cg * 2 + j2 * 32];
                w[j2 * 2] = wv.x;
                w[j2 * 2 + 1] = wv.y;
            }
#pragma unroll
            for (int i = 0; i < 4; ++i) {
                float ai = ((const float*)&av[i])[kk];
#pragma unroll
                for (int j = 0; j < 8; ++j) acc[i][j] += ai * w[j];
            }
        }
    }

#pragma unroll
    for (int i = 0; i < 4; ++i) {
        int r = row0 + i;
        if (r >= nrows) continue;
#pragma unroll
        for (int j2 = 0; j2 < 4; ++j2) {
            float2 st;
#pragma unroll
            for (int j1 = 0; j1 < 2; ++j1) {
                int c = cg * 2 + j1 + j2 * 32;
                float v = acc[i][j2 * 2 + j1] + bias[c];
                if (EPI >= 1) v = v > 0.f ? v : 0.2f * v;
                if (EPI == 2) v = gg[c] * v * BNS + bb[c];
                ((float*)&st)[j1] = v;
            }
            *(float2*)&out[r * 128 + cg * 2 + j2 * 32] = st;
        }
    }
}

// ---------------- vn MLP: vn += leaky((acc/denom)@W1+b1)@W2 + b2 ----------------
__global__ __launch_bounds__(256) void k_vn_mlp(
    const float* __restrict__ vnacc, const float* __restrict__ counts,
    const float* __restrict__ W1, const float* __restrict__ b1,
    const float* __restrict__ W2, const float* __restrict__ b2,
    float* __restrict__ vn) {
    __shared__ float sW[128 * 128];
    __shared__ float sT[32 * 128];
    const int t = threadIdx.x;
    const int r0 = blockIdx.x * 32;
    {
        const float4* W4 = (const float4*)W1;
        float4* sW4 = (float4*)sW;
#pragma unroll
        for (int i = 0; i < 16; ++i) sW4[t + 256 * i] = W4[t + 256 * i];
    }
    __syncthreads();
    const int cg = t & 15;
    const int rp = t >> 4;  // 0..15, 2 rows each
    const int ra = r0 + rp * 2, rb = ra + 1;
    const float inva = 1.f / fmaxf(counts[ra], 1.f);
    const float invb = 1.f / fmaxf(counts[rb], 1.f);

    float acc[2][8];
#pragma unroll
    for (int i = 0; i < 2; ++i)
#pragma unroll
        for (int j = 0; j < 8; ++j) acc[i][j] = 0.f;

    for (int k = 0; k < 128; ++k) {
        float a0 = vnacc[ra * 128 + k], a1 = vnacc[rb * 128 + k];
#pragma unroll
        for (int j2 = 0; j2 < 4; ++j2) {
            float2 wv = *(const float2*)&sW[k * 128 + cg * 2 + j2 * 32];
            acc[0][j2 * 2] += a0 * wv.x; acc[0][j2 * 2 + 1] += a0 * wv.y;
            acc[1][j2 * 2] += a1 * wv.x; acc[1][j2 * 2 + 1] += a1 * wv.y;
        }
    }
#pragma unroll
    for (int j2 = 0; j2 < 4; ++j2)
#pragma unroll
        for (int j1 = 0; j1 < 2; ++j1) {
            int c = cg * 2 + j1 + j2 * 32;
            float v0 = acc[0][j2 * 2 + j1] * inva + b1[c];
            v0 = v0 > 0.f ? v0 : 0.2f * v0;
            float v1 = acc[1][j2 * 2 + j1] * invb + b1[c];
            v1 = v1 > 0.f ? v1 : 0.2f * v1;
            sT[(rp * 2) * 128 + c] = v0;
            sT[(rp * 2 + 1) * 128 + c] = v1;
        }
    __syncthreads();
    {
        const float4* W4 = (const float4*)W2;
        float4* sW4 = (float4*)sW;
#pragma unroll
        for (int i = 0; i < 16; ++i) sW4[t + 256 * i] = W4[t + 256 * i];
    }
    __syncthreads();
    float acc2[2][8];
#pragma unroll
    for (int i = 0; i < 2; ++i)
#pragma unroll
        for (int j = 0; j < 8; ++j) acc2[i][j] = 0.f;
    for (int k = 0; k < 128; ++k) {
        float a0 = sT[(rp * 2) * 128 + k], a1 = sT[(rp * 2 + 1) * 128 + k];
#pragma unroll
        for (int j2 = 0; j2 < 4; ++j2) {
            float2 wv = *(const float2*)&sW[k * 128 + cg * 2 + j2 * 32];
            acc2[0][j2 * 2] += a0 * wv.x; acc2[0][j2 * 2 + 1] += a0 * wv.y;
            acc2[1][j2 * 2] += a1 * wv.x; acc2[1][j2 * 2 + 1] += a1 * wv.y;
        }
    }
#pragma unroll
    for (int j2 = 0; j2 < 4; ++j2)
#pragma unroll
        for (int j1 = 0; j1 < 2; ++j1) {
            int c = cg * 2 + j1 + j2 * 32;
            vn[ra * 128 + c] += acc2[0][j2 * 2 + j1] + b2[c];
            vn[rb * 128 + c] += acc2[1][j2 * 2 + j1] + b2[c];
        }
}

// ---------------- final: out = bn(pool) @ fcW^T + fcb ----------------
__global__ __launch_bounds__(256) void k_final(
    const float* __restrict__ pooled, const float* __restrict__ g,
    const float* __restrict__ b, const float* __restrict__ fcW,
    const float* __restrict__ fcb, float* __restrict__ out) {
    __shared__ float sP[4 * 128];
    const int t = threadIdx.x;
    for (int i = t; i < 512; i += 256) {
        int rr = i >> 7, c = i & 127;
        float v = pooled[(blockIdx.x * 4 + rr) * 128 + c];
        sP[i] = g[c] * v * BNS + b[c];
    }
    __syncthreads();
    const int brow = blockIdx.x * 4 + (t >> 6);
    const int o = t & 63;
    float acc = fcb[o];
    const float* wrow = fcW + o * 128;
    const float* prow = sP + (t >> 6) * 128;
    for (int k = 0; k < 128; ++k) acc += prow[k] * wrow[k];
    out[brow * 64 + o] = acc;
}

extern "C" void kernel_launch(void* const* d_in, const int* in_sizes, int n_in,
                              void* d_out, int out_size, void* d_ws, size_t ws_size,
                              hipStream_t stream) {
    const float* x       = (const float*)d_in[0];
    const int*   ei      = (const int*)d_in[1];
    const int*   batch   = (const int*)d_in[2];
    const float* node_W  = (const float*)d_in[3];
    const float* node_b  = (const float*)d_in[4];
    const float* conv_W1 = (const float*)d_in[5];
    const float* conv_b1 = (const float*)d_in[6];
    const float* conv_g  = (const float*)d_in[7];
    const float* conv_bt = (const float*)d_in[8];
    const float* conv_W2 = (const float*)d_in[9];
    const float* conv_b2 = (const float*)d_in[10];
    const float* vn_emb  = (const float*)d_in[11];
    const float* vn_W1   = (const float*)d_in[12];
    const float* vn_b1   = (const float*)d_in[13];
    const float* vn_W2   = (const float*)d_in[14];
    const float* vn_b2   = (const float*)d_in[15];
    const float* bn_g    = (const float*)d_in[16];
    const float* bn_b    = (const float*)d_in[17];
    const float* fc_W    = (const float*)d_in[18];
    const float* fc_b    = (const float*)d_in[19];
    float* out = (float*)d_out;

    float* ws = (float*)d_ws;
    float* h      = ws;                    // NN*128
    float* agg    = h + (size_t)NN * 128;  // NN*128
    float* vn     = agg + (size_t)NN * 128;  // NB*128
    float* vnacc  = vn + NB * 128;           // NB*128
    float* counts = vnacc + NB * 128;        // NB

    hipMemsetAsync(counts, 0, NB * sizeof(float), stream);
    k_count<<<(NN + 255) / 256, 256, 0, stream>>>(batch, counts);
    k_vn_init<<<(NB * 128) / 256, 256, 0, stream>>>(vn_emb, vn);

    // node encoder: h = x @ node_W + node_b
    k_gemm128<0, false><<<(NN + 63) / 64, 256, 0, stream>>>(
        x, nullptr, node_W, node_b, nullptr, nullptr, h, NN);

    for (int l = 0; l < 3; ++l) {
        k_addvn<<<(NN * 32) / 256, 256, 0, stream>>>(h, vn, batch);
        hipMemsetAsync(agg, 0, (size_t)NN * 128 * sizeof(float), stream);
        k_scatter<<<(NE * 32) / 256, 256, 0, stream>>>(ei, h, agg);
        // z = bn(leaky((h+agg) @ W1 + b1))  -> write into agg
        k_gemm128<2, true><<<(NN + 63) / 64, 256, 0, stream>>>(
            h, agg, conv_W1 + l * 16384, conv_b1 + l * 128,
            conv_g + l * 128, conv_bt + l * 128, agg, NN);
        // h = leaky(z @ W2 + b2)
        k_gemm128<1, false><<<(NN + 63) / 64, 256, 0, stream>>>(
            agg, nullptr, conv_W2 + l * 16384, conv_b2 + l * 128,
            nullptr, nullptr, h, NN);
        hipMemsetAsync(vnacc, 0, NB * 128 * sizeof(float), stream);
        k_pool<<<(NN * 32) / 256, 256, 0, stream>>>(h, batch, vnacc);
        k_vn_mlp<<<NB / 32, 256, 0, stream>>>(
            vnacc, counts, vn_W1 + l * 16384, vn_b1 + l * 128,
            vn_W2 + l * 16384, vn_b2 + l * 128, vn);
    }

    hipMemsetAsync(vnacc, 0, NB * 128 * sizeof(float), stream);
    k_pool<<<(NN * 32) / 256, 256, 0, stream>>>(h, batch, vnacc);
    k_final<<<NB / 4, 256, 0, stream>>>(vnacc, bn_g, bn_b, fc_W, fc_b, out);
}

// Round 2
// 710.553 us; speedup vs baseline: 6.8613x; 6.8613x over previous
//
#include <hip/hip_runtime.h>
#include <hip/hip_bf16.h>

#define NN 50000
#define NE 800000
#define NB 512

constexpr float BNS = 0.9999950000374998f;  // 1/sqrt(1+1e-5)

// ---------------- vn init ----------------
__global__ void k_vn_init(const float* __restrict__ vn_emb, float* __restrict__ vn) {
    int idx = blockIdx.x * 256 + threadIdx.x;  // < NB*128
    vn[idx] = vn_emb[idx & 127];
}

// ---------------- h += vn[batch] ----------------
__global__ void k_addvn(float* __restrict__ h, const float* __restrict__ vn,
                        const int* __restrict__ batch) {
    int idx = blockIdx.x * 256 + threadIdx.x;  // < NN*32
    int i = idx >> 5, q = idx & 31;
    float4 v = ((float4*)h)[idx];
    float4 u = ((const float4*)vn)[batch[i] * 32 + q];
    v.x += u.x; v.y += u.y; v.z += u.z; v.w += u.w;
    ((float4*)h)[idx] = v;
}

// ---------------- batch ranges (batch is sorted) ----------------
__global__ void k_bstart(const int* __restrict__ batch, int* __restrict__ bstart) {
    int b = blockIdx.x * 256 + threadIdx.x;
    if (b > NB) return;
    int lo = 0, hi = NN;
    while (lo < hi) { int m = (lo + hi) >> 1; if (batch[m] < b) lo = m + 1; else hi = m; }
    bstart[b] = lo;
}

__global__ void k_counts(const int* __restrict__ bstart, float* __restrict__ counts) {
    int b = blockIdx.x * 256 + threadIdx.x;
    if (b < NB) counts[b] = (float)(bstart[b + 1] - bstart[b]);
}

// ---------------- CSR build (by dst) ----------------
__global__ void k_deg(const int* __restrict__ ei, int* __restrict__ deg) {
    int e = blockIdx.x * 256 + threadIdx.x;
    if (e < NE) atomicAdd(&deg[ei[NE + e]], 1);
}

__global__ void k_scan(const int* __restrict__ deg, int* __restrict__ off) {
    // single block, 256 threads, CHUNK=196 (256*196 = 50176 >= 50000)
    __shared__ int part[256];
    const int t = threadIdx.x;
    const int begin = t * 196;
    const int end = min(begin + 196, NN);
    int s = 0;
    for (int i = begin; i < end; ++i) s += deg[i];
    part[t] = s;
    __syncthreads();
    for (int d = 1; d < 256; d <<= 1) {
        int v = (t >= d) ? part[t - d] : 0;
        __syncthreads();
        part[t] += v;
        __syncthreads();
    }
    int run = (t == 0) ? 0 : part[t - 1];
    for (int i = begin; i < end; ++i) { off[i] = run; run += deg[i]; }
    if (t == 255) off[NN] = run;
}

__global__ void k_copy(const int* __restrict__ off, int* __restrict__ cursor) {
    int i = blockIdx.x * 256 + threadIdx.x;
    if (i < NN) cursor[i] = off[i];
}

__global__ void k_fill(const int* __restrict__ ei, int* __restrict__ cursor,
                       int* __restrict__ csr) {
    int e = blockIdx.x * 256 + threadIdx.x;
    if (e < NE) {
        int pos = atomicAdd(&cursor[ei[NE + e]], 1);
        csr[pos] = ei[e];
    }
}

// ---------------- gather: agg[d] = h[d] + sum_{src in N(d)} h[src] ----------------
__global__ __launch_bounds__(256) void k_gather(
    const int* __restrict__ off, const int* __restrict__ csr,
    const float* __restrict__ h, float* __restrict__ agg) {
    int node = blockIdx.x * 8 + (threadIdx.x >> 5);
    int q = threadIdx.x & 31;
    if (node >= NN) return;
    const float4* h4 = (const float4*)h;
    int s = off[node], e = off[node + 1];
    float4 a = h4[node * 32 + q];
    float4 b = make_float4(0.f, 0.f, 0.f, 0.f);
    int j = s;
    for (; j + 1 < e; j += 2) {
        int s0 = csr[j], s1 = csr[j + 1];
        float4 v0 = h4[s0 * 32 + q];
        float4 v1 = h4[s1 * 32 + q];
        a.x += v0.x; a.y += v0.y; a.z += v0.z; a.w += v0.w;
        b.x += v1.x; b.y += v1.y; b.z += v1.z; b.w += v1.w;
    }
    if (j < e) {
        int s0 = csr[j];
        float4 v0 = h4[s0 * 32 + q];
        a.x += v0.x; a.y += v0.y; a.z += v0.z; a.w += v0.w;
    }
    a.x += b.x; a.y += b.y; a.z += b.z; a.w += b.w;
    ((float4*)agg)[node * 32 + q] = a;
}

// ---------------- GEMM: out = epi(A @ W + bias) ----------------
// A [nrows,128] row-major, W [128,128] row-major (k,out), out [nrows,128]
// EPI: 0 = none, 1 = leaky, 2 = bn(leaky(x))
template <int EPI>
__global__ __launch_bounds__(256) void k_gemm128(
    const float* __restrict__ A, const float* __restrict__ W,
    const float* __restrict__ bias, const float* __restrict__ gg,
    const float* __restrict__ bb, float* __restrict__ out, int nrows) {
    __shared__ float sW[64 * 128];  // 32 KB: one K-half of W
    const int t = threadIdx.x;
    const int cg = t & 15;   // column group: cols = cg*2 + j1 + 32*j2
    const int rq = t >> 4;   // row quad 0..15
    const int row0 = blockIdx.x * 64 + rq * 4;

    float acc[4][8];
#pragma unroll
    for (int i = 0; i < 4; ++i)
#pragma unroll
        for (int j = 0; j < 8; ++j) acc[i][j] = 0.f;

    const float4* A4 = (const float4*)A;
    int rl[4];
#pragma unroll
    for (int i = 0; i < 4; ++i) rl[i] = min(row0 + i, nrows - 1);

    for (int kh = 0; kh < 2; ++kh) {
        {
            const float4* W4 = (const float4*)(W + kh * 8192);
            float4* sW4 = (float4*)sW;
#pragma unroll
            for (int i = 0; i < 8; ++i) sW4[t + 256 * i] = W4[t + 256 * i];
        }
        __syncthreads();
#pragma unroll 2
        for (int k4 = 0; k4 < 16; ++k4) {
            float4 av[4];
#pragma unroll
            for (int i = 0; i < 4; ++i) av[i] = A4[rl[i] * 32 + kh * 16 + k4];
#pragma unroll
            for (int kk = 0; kk < 4; ++kk) {
                const int k = k4 * 4 + kk;
                float w[8];
#pragma unroll
                for (int j2 = 0; j2 < 4; ++j2) {
                    float2 wv = *(const float2*)&sW[k * 128 + cg * 2 + j2 * 32];
                    w[j2 * 2] = wv.x;
                    w[j2 * 2 + 1] = wv.y;
                }
#pragma unroll
                for (int i = 0; i < 4; ++i) {
                    float ai = ((const float*)&av[i])[kk];
#pragma unroll
                    for (int j = 0; j < 8; ++j) acc[i][j] += ai * w[j];
                }
            }
        }
        __syncthreads();
    }

#pragma unroll
    for (int i = 0; i < 4; ++i) {
        int r = row0 + i;
        if (r >= nrows) continue;
#pragma unroll
        for (int j2 = 0; j2 < 4; ++j2) {
            float2 st;
#pragma unroll
            for (int j1 = 0; j1 < 2; ++j1) {
                int c = cg * 2 + j1 + j2 * 32;
                float v = acc[i][j2 * 2 + j1] + bias[c];
                if (EPI >= 1) v = v > 0.f ? v : 0.2f * v;
                if (EPI == 2) v = gg[c] * v * BNS + bb[c];
                ((float*)&st)[j1] = v;
            }
            *(float2*)&out[r * 128 + cg * 2 + j2 * 32] = st;
        }
    }
}

// ---------------- segmented pool: acc[b] = sum of h rows in [bstart[b], bstart[b+1]) ----------------
__global__ __launch_bounds__(256) void k_pool2(
    const float* __restrict__ h, const int* __restrict__ bstart,
    float* __restrict__ acc) {
    const int b = blockIdx.x;
    const int s = bstart[b], e = bstart[b + 1];
    const int g = threadIdx.x >> 5;  // 8 row-groups
    const int q = threadIdx.x & 31;  // float4 chunk
    const float4* h4 = (const float4*)h;
    float4 a = make_float4(0.f, 0.f, 0.f, 0.f);
    for (int r = s + g; r < e; r += 8) {
        float4 v = h4[r * 32 + q];
        a.x += v.x; a.y += v.y; a.z += v.z; a.w += v.w;
    }
    __shared__ float4 red[8][32];
    red[g][q] = a;
    __syncthreads();
    if (g == 0) {
#pragma unroll
        for (int g2 = 1; g2 < 8; ++g2) {
            float4 v = red[g2][q];
            a.x += v.x; a.y += v.y; a.z += v.z; a.w += v.w;
        }
        ((float4*)acc)[b * 32 + q] = a;
    }
}

// ---------------- vn MLP: vn += leaky((acc/denom)@W1+b1)@W2 + b2 ----------------
__global__ __launch_bounds__(256) void k_vn_mlp(
    const float* __restrict__ vnacc, const float* __restrict__ counts,
    const float* __restrict__ W1, const float* __restrict__ b1,
    const float* __restrict__ W2, const float* __restrict__ b2,
    float* __restrict__ vn) {
    __shared__ float sW[128 * 128];
    __shared__ float sT[32 * 128];
    const int t = threadIdx.x;
    const int r0 = blockIdx.x * 32;
    {
        const float4* W4 = (const float4*)W1;
        float4* sW4 = (float4*)sW;
#pragma unroll
        for (int i = 0; i < 16; ++i) sW4[t + 256 * i] = W4[t + 256 * i];
    }
    __syncthreads();
    const int cg = t & 15;
    const int rp = t >> 4;  // 0..15, 2 rows each
    const int ra = r0 + rp * 2, rb = ra + 1;
    const float inva = 1.f / fmaxf(counts[ra], 1.f);
    const float invb = 1.f / fmaxf(counts[rb], 1.f);

    float acc[2][8];
#pragma unroll
    for (int i = 0; i < 2; ++i)
#pragma unroll
        for (int j = 0; j < 8; ++j) acc[i][j] = 0.f;

    for (int k = 0; k < 128; ++k) {
        float a0 = vnacc[ra * 128 + k], a1 = vnacc[rb * 128 + k];
#pragma unroll
        for (int j2 = 0; j2 < 4; ++j2) {
            float2 wv = *(const float2*)&sW[k * 128 + cg * 2 + j2 * 32];
            acc[0][j2 * 2] += a0 * wv.x; acc[0][j2 * 2 + 1] += a0 * wv.y;
            acc[1][j2 * 2] += a1 * wv.x; acc[1][j2 * 2 + 1] += a1 * wv.y;
        }
    }
#pragma unroll
    for (int j2 = 0; j2 < 4; ++j2)
#pragma unroll
        for (int j1 = 0; j1 < 2; ++j1) {
            int c = cg * 2 + j1 + j2 * 32;
            float v0 = acc[0][j2 * 2 + j1] * inva + b1[c];
            v0 = v0 > 0.f ? v0 : 0.2f * v0;
            float v1 = acc[1][j2 * 2 + j1] * invb + b1[c];
            v1 = v1 > 0.f ? v1 : 0.2f * v1;
            sT[(rp * 2) * 128 + c] = v0;
            sT[(rp * 2 + 1) * 128 + c] = v1;
        }
    __syncthreads();
    {
        const float4* W4 = (const float4*)W2;
        float4* sW4 = (float4*)sW;
#pragma unroll
        for (int i = 0; i < 16; ++i) sW4[t + 256 * i] = W4[t + 256 * i];
    }
    __syncthreads();
    float acc2[2][8];
#pragma unroll
    for (int i = 0; i < 2; ++i)
#pragma unroll
        for (int j = 0; j < 8; ++j) acc2[i][j] = 0.f;
    for (int k = 0; k < 128; ++k) {
        float a0 = sT[(rp * 2) * 128 + k], a1 = sT[(rp * 2 + 1) * 128 + k];
#pragma unroll
        for (int j2 = 0; j2 < 4; ++j2) {
            float2 wv = *(const float2*)&sW[k * 128 + cg * 2 + j2 * 32];
            acc2[0][j2 * 2] += a0 * wv.x; acc2[0][j2 * 2 + 1] += a0 * wv.y;
            acc2[1][j2 * 2] += a1 * wv.x; acc2[1][j2 * 2 + 1] += a1 * wv.y;
        }
    }
#pragma unroll
    for (int j2 = 0; j2 < 4; ++j2)
#pragma unroll
        for (int j1 = 0; j1 < 2; ++j1) {
            int c = cg * 2 + j1 + j2 * 32;
            vn[ra * 128 + c] += acc2[0][j2 * 2 + j1] + b2[c];
            vn[rb * 128 + c] += acc2[1][j2 * 2 + j1] + b2[c];
        }
}

// ---------------- final: out = bn(pool) @ fcW^T + fcb ----------------
__global__ __launch_bounds__(256) void k_final(
    const float* __restrict__ pooled, const float* __restrict__ g,
    const float* __restrict__ b, const float* __restrict__ fcW,
    const float* __restrict__ fcb, float* __restrict__ out) {
    __shared__ float sP[4 * 128];
    const int t = threadIdx.x;
    for (int i = t; i < 512; i += 256) {
        int rr = i >> 7, c = i & 127;
        float v = pooled[(blockIdx.x * 4 + rr) * 128 + c];
        sP[i] = g[c] * v * BNS + b[c];
    }
    __syncthreads();
    const int brow = blockIdx.x * 4 + (t >> 6);
    const int o = t & 63;
    float acc = fcb[o];
    const float* wrow = fcW + o * 128;
    const float* prow = sP + (t >> 6) * 128;
    for (int k = 0; k < 128; ++k) acc += prow[k] * wrow[k];
    out[brow * 64 + o] = acc;
}

extern "C" void kernel_launch(void* const* d_in, const int* in_sizes, int n_in,
                              void* d_out, int out_size, void* d_ws, size_t ws_size,
                              hipStream_t stream) {
    const float* x       = (const float*)d_in[0];
    const int*   ei      = (const int*)d_in[1];
    const int*   batch   = (const int*)d_in[2];
    const float* node_W  = (const float*)d_in[3];
    const float* node_b  = (const float*)d_in[4];
    const float* conv_W1 = (const float*)d_in[5];
    const float* conv_b1 = (const float*)d_in[6];
    const float* conv_g  = (const float*)d_in[7];
    const float* conv_bt = (const float*)d_in[8];
    const float* conv_W2 = (const float*)d_in[9];
    const float* conv_b2 = (const float*)d_in[10];
    const float* vn_emb  = (const float*)d_in[11];
    const float* vn_W1   = (const float*)d_in[12];
    const float* vn_b1   = (const float*)d_in[13];
    const float* vn_W2   = (const float*)d_in[14];
    const float* vn_b2   = (const float*)d_in[15];
    const float* bn_g    = (const float*)d_in[16];
    const float* bn_b    = (const float*)d_in[17];
    const float* fc_W    = (const float*)d_in[18];
    const float* fc_b    = (const float*)d_in[19];
    float* out = (float*)d_out;

    float* ws = (float*)d_ws;
    float* h      = ws;                       // NN*128
    float* agg    = h + (size_t)NN * 128;     // NN*128
    float* vn     = agg + (size_t)NN * 128;   // NB*128
    float* vnacc  = vn + NB * 128;            // NB*128
    float* counts = vnacc + NB * 128;         // NB
    int* deg    = (int*)(counts + NB);        // NN
    int* off    = deg + NN;                   // NN+1
    int* cursor = off + NN + 1;               // NN
    int* csr    = cursor + NN;                // NE
    int* bstart = csr + NE;                   // NB+1

    // ---- static structure: CSR by dst, batch ranges ----
    hipMemsetAsync(deg, 0, NN * sizeof(int), stream);
    k_deg<<<(NE + 255) / 256, 256, 0, stream>>>(ei, deg);
    k_scan<<<1, 256, 0, stream>>>(deg, off);
    k_copy<<<(NN + 255) / 256, 256, 0, stream>>>(off, cursor);
    k_fill<<<(NE + 255) / 256, 256, 0, stream>>>(ei, cursor, csr);
    k_bstart<<<3, 256, 0, stream>>>(batch, bstart);
    k_counts<<<2, 256, 0, stream>>>(bstart, counts);
    k_vn_init<<<(NB * 128) / 256, 256, 0, stream>>>(vn_emb, vn);

    // node encoder: h = x @ node_W + node_b
    k_gemm128<0><<<(NN + 63) / 64, 256, 0, stream>>>(
        x, node_W, node_b, nullptr, nullptr, h, NN);

    for (int l = 0; l < 3; ++l) {
        k_addvn<<<(NN * 32) / 256, 256, 0, stream>>>(h, vn, batch);
        // agg = h + sum of neighbor h (fuses the GIN self-add)
        k_gather<<<(NN + 7) / 8, 256, 0, stream>>>(off, csr, h, agg);
        // z = bn(leaky(agg @ W1 + b1))  (in-place agg)
        k_gemm128<2><<<(NN + 63) / 64, 256, 0, stream>>>(
            agg, conv_W1 + l * 16384, conv_b1 + l * 128,
            conv_g + l * 128, conv_bt + l * 128, agg, NN);
        // h = leaky(z @ W2 + b2)
        k_gemm128<1><<<(NN + 63) / 64, 256, 0, stream>>>(
            agg, conv_W2 + l * 16384, conv_b2 + l * 128,
            nullptr, nullptr, h, NN);
        k_pool2<<<NB, 256, 0, stream>>>(h, bstart, vnacc);
        k_vn_mlp<<<NB / 32, 256, 0, stream>>>(
            vnacc, counts, vn_W1 + l * 16384, vn_b1 + l * 128,
            vn_W2 + l * 16384, vn_b2 + l * 128, vn);
    }

    k_pool2<<<NB, 256, 0, stream>>>(h, bstart, vnacc);
    k_final<<<NB / 4, 256, 0, stream>>>(vnacc, bn_g, bn_b, fc_W, fc_b, out);
}

// Round 3
// 640.759 us; speedup vs baseline: 7.6087x; 1.1089x over previous
//
#include <hip/hip_runtime.h>
#include <hip/hip_bf16.h>

#define NN 50000
#define NE 800000
#define NB 512
#define NSCB 196  // scan blocks: 196*256 = 50176 >= NN

constexpr float BNS = 0.9999950000374998f;  // 1/sqrt(1+1e-5)

// ---------------- vn init ----------------
__global__ void k_vn_init(const float* __restrict__ vn_emb, float* __restrict__ vn) {
    int idx = blockIdx.x * 256 + threadIdx.x;  // < NB*128
    vn[idx] = vn_emb[idx & 127];
}

// ---------------- h += vn[batch] ----------------
__global__ void k_addvn(float* __restrict__ h, const float* __restrict__ vn,
                        const int* __restrict__ batch) {
    int idx = blockIdx.x * 256 + threadIdx.x;  // < NN*32
    int i = idx >> 5, q = idx & 31;
    float4 v = ((float4*)h)[idx];
    float4 u = ((const float4*)vn)[batch[i] * 32 + q];
    v.x += u.x; v.y += u.y; v.z += u.z; v.w += u.w;
    ((float4*)h)[idx] = v;
}

// ---------------- batch ranges (batch is sorted) ----------------
__global__ void k_bstart(const int* __restrict__ batch, int* __restrict__ bstart) {
    int b = blockIdx.x * 256 + threadIdx.x;
    if (b > NB) return;
    int lo = 0, hi = NN;
    while (lo < hi) { int m = (lo + hi) >> 1; if (batch[m] < b) lo = m + 1; else hi = m; }
    bstart[b] = lo;
}

__global__ void k_counts(const int* __restrict__ bstart, float* __restrict__ counts) {
    int b = blockIdx.x * 256 + threadIdx.x;
    if (b < NB) counts[b] = (float)(bstart[b + 1] - bstart[b]);
}

// ---------------- CSR build (by dst) ----------------
__global__ void k_deg(const int* __restrict__ ei, int* __restrict__ deg) {
    int e = blockIdx.x * 256 + threadIdx.x;
    if (e < NE) atomicAdd(&deg[ei[NE + e]], 1);
}

// pass 1: per-block sums
__global__ void k_scan1(const int* __restrict__ deg, int* __restrict__ part) {
    __shared__ int s[256];
    const int t = threadIdx.x;
    int i = blockIdx.x * 256 + t;
    s[t] = i < NN ? deg[i] : 0;
    __syncthreads();
    for (int d = 128; d > 0; d >>= 1) {
        if (t < d) s[t] += s[t + d];
        __syncthreads();
    }
    if (t == 0) part[blockIdx.x] = s[0];
}

// pass 2: exclusive scan of block sums (single block)
__global__ void k_scan2(int* __restrict__ part, int* __restrict__ off) {
    __shared__ int s[256];
    const int t = threadIdx.x;
    s[t] = t < NSCB ? part[t] : 0;
    __syncthreads();
    for (int d = 1; d < 256; d <<= 1) {
        int v = (t >= d) ? s[t - d] : 0;
        __syncthreads();
        s[t] += v;
        __syncthreads();
    }
    if (t < NSCB) part[t] = t ? s[t - 1] : 0;  // exclusive block offsets
    if (t == NSCB - 1) off[NN] = s[t];         // total
}

// pass 3: in-block exclusive scan + block offset -> off, cursor
__global__ void k_scan3(const int* __restrict__ deg, const int* __restrict__ part,
                        int* __restrict__ off, int* __restrict__ cursor) {
    __shared__ int s[256];
    const int t = threadIdx.x;
    int i = blockIdx.x * 256 + t;
    int v = i < NN ? deg[i] : 0;
    s[t] = v;
    __syncthreads();
    for (int d = 1; d < 256; d <<= 1) {
        int u = (t >= d) ? s[t - d] : 0;
        __syncthreads();
        s[t] += u;
        __syncthreads();
    }
    if (i < NN) {
        int ex = part[blockIdx.x] + s[t] - v;
        off[i] = ex;
        cursor[i] = ex;
    }
}

__global__ void k_fill(const int* __restrict__ ei, int* __restrict__ cursor,
                       int* __restrict__ csr) {
    int e = blockIdx.x * 256 + threadIdx.x;
    if (e < NE) {
        int pos = atomicAdd(&cursor[ei[NE + e]], 1);
        csr[pos] = ei[e];
    }
}

// ---------------- gather: agg[d] = h[d] + sum_{src in N(d)} h[src] ----------------
__global__ __launch_bounds__(256) void k_gather(
    const int* __restrict__ off, const int* __restrict__ csr,
    const float* __restrict__ h, float* __restrict__ agg) {
    int node = blockIdx.x * 8 + (threadIdx.x >> 5);
    int q = threadIdx.x & 31;
    if (node >= NN) return;
    const float4* h4 = (const float4*)h;
    int s = off[node], e = off[node + 1];
    float4 a = h4[node * 32 + q];
    float4 b = make_float4(0.f, 0.f, 0.f, 0.f);
    int j = s;
    for (; j + 1 < e; j += 2) {
        int s0 = csr[j], s1 = csr[j + 1];
        float4 v0 = h4[s0 * 32 + q];
        float4 v1 = h4[s1 * 32 + q];
        a.x += v0.x; a.y += v0.y; a.z += v0.z; a.w += v0.w;
        b.x += v1.x; b.y += v1.y; b.z += v1.z; b.w += v1.w;
    }
    if (j < e) {
        int s0 = csr[j];
        float4 v0 = h4[s0 * 32 + q];
        a.x += v0.x; a.y += v0.y; a.z += v0.z; a.w += v0.w;
    }
    a.x += b.x; a.y += b.y; a.z += b.z; a.w += b.w;
    ((float4*)agg)[node * 32 + q] = a;
}

// ---------------- GEMM: out = epi(A @ W + bias) ----------------
// A [nrows,128] row-major, W [128,128] row-major (k,out), out [nrows,128]
// 128x128 tile / block, 256 threads, 8x8 per thread, A+W staged in LDS.
// EPI: 0 = none, 1 = leaky, 2 = bn(leaky(x))
template <int EPI>
__global__ __launch_bounds__(256) void k_gemm128(
    const float* __restrict__ A, const float* __restrict__ W,
    const float* __restrict__ bias, const float* __restrict__ gg,
    const float* __restrict__ bb, float* __restrict__ out, int nrows) {
    __shared__ float sA[32][128];  // [k][row] 16 KB
    __shared__ float sW[32][128];  // [k][col] 16 KB
    const int t = threadIdx.x;
    const int cx = t & 15;   // col group: cols cx*8 .. cx*8+7
    const int ry = t >> 4;   // row group: rows ry*8 .. ry*8+7
    const int row0 = blockIdx.x * 128;

    // staging indices
    const int a_r = t >> 3;          // 0..31 (+32 per pass)
    const int a_k4 = t & 7;          // float4 index within 32-k chunk
    const int w_k = t >> 5;          // 0..7 (+8 per pass)
    const int w_c4 = t & 31;         // float4 col index

    const float4* A4 = (const float4*)A;
    const float4* W4 = (const float4*)W;

    float4 ra[4], rw[4];
    int arow[4];
#pragma unroll
    for (int p = 0; p < 4; ++p) arow[p] = min(row0 + p * 32 + a_r, nrows - 1);

    auto load_gl = [&](int kc) {
#pragma unroll
        for (int p = 0; p < 4; ++p) ra[p] = A4[arow[p] * 32 + kc * 8 + a_k4];
#pragma unroll
        for (int p = 0; p < 4; ++p) rw[p] = W4[(kc * 32 + p * 8 + w_k) * 32 + w_c4];
    };
    auto store_lds = [&]() {
#pragma unroll
        for (int p = 0; p < 4; ++p) {
            int r = p * 32 + a_r;
            sA[a_k4 * 4 + 0][r] = ra[p].x;
            sA[a_k4 * 4 + 1][r] = ra[p].y;
            sA[a_k4 * 4 + 2][r] = ra[p].z;
            sA[a_k4 * 4 + 3][r] = ra[p].w;
        }
#pragma unroll
        for (int p = 0; p < 4; ++p)
            *(float4*)&sW[p * 8 + w_k][w_c4 * 4] = rw[p];
    };

    float acc[8][8];
#pragma unroll
    for (int i = 0; i < 8; ++i)
#pragma unroll
        for (int j = 0; j < 8; ++j) acc[i][j] = 0.f;

    load_gl(0);
    for (int kc = 0; kc < 4; ++kc) {
        store_lds();
        __syncthreads();
        if (kc < 3) load_gl(kc + 1);
#pragma unroll 4
        for (int k = 0; k < 32; ++k) {
            float4 a0 = *(const float4*)&sA[k][ry * 8];
            float4 a1 = *(const float4*)&sA[k][ry * 8 + 4];
            float4 w0 = *(const float4*)&sW[k][cx * 8];
            float4 w1 = *(const float4*)&sW[k][cx * 8 + 4];
            const float* ap = (const float*)&a0;
            const float* ap1 = (const float*)&a1;
            const float* wp = (const float*)&w0;
            const float* wp1 = (const float*)&w1;
#pragma unroll
            for (int i = 0; i < 4; ++i)
#pragma unroll
                for (int j = 0; j < 4; ++j) {
                    acc[i][j] += ap[i] * wp[j];
                    acc[i][j + 4] += ap[i] * wp1[j];
                    acc[i + 4][j] += ap1[i] * wp[j];
                    acc[i + 4][j + 4] += ap1[i] * wp1[j];
                }
        }
        __syncthreads();
    }

#pragma unroll
    for (int i = 0; i < 8; ++i) {
        int r = row0 + ry * 8 + i;
        if (r >= nrows) continue;
#pragma unroll
        for (int j4 = 0; j4 < 2; ++j4) {
            float4 st;
#pragma unroll
            for (int j = 0; j < 4; ++j) {
                int c = cx * 8 + j4 * 4 + j;
                float v = acc[i][j4 * 4 + j] + bias[c];
                if (EPI >= 1) v = v > 0.f ? v : 0.2f * v;
                if (EPI == 2) v = gg[c] * v * BNS + bb[c];
                ((float*)&st)[j] = v;
            }
            *(float4*)&out[r * 128 + cx * 8 + j4 * 4] = st;
        }
    }
}

// ---------------- segmented pool ----------------
__global__ __launch_bounds__(256) void k_pool2(
    const float* __restrict__ h, const int* __restrict__ bstart,
    float* __restrict__ acc) {
    const int b = blockIdx.x;
    const int s = bstart[b], e = bstart[b + 1];
    const int g = threadIdx.x >> 5;  // 8 row-groups
    const int q = threadIdx.x & 31;  // float4 chunk
    const float4* h4 = (const float4*)h;
    float4 a = make_float4(0.f, 0.f, 0.f, 0.f);
    for (int r = s + g; r < e; r += 8) {
        float4 v = h4[r * 32 + q];
        a.x += v.x; a.y += v.y; a.z += v.z; a.w += v.w;
    }
    __shared__ float4 red[8][32];
    red[g][q] = a;
    __syncthreads();
    if (g == 0) {
#pragma unroll
        for (int g2 = 1; g2 < 8; ++g2) {
            float4 v = red[g2][q];
            a.x += v.x; a.y += v.y; a.z += v.z; a.w += v.w;
        }
        ((float4*)acc)[b * 32 + q] = a;
    }
}

// ---------------- vn MLP ----------------
__global__ __launch_bounds__(256) void k_vn_mlp(
    const float* __restrict__ vnacc, const float* __restrict__ counts,
    const float* __restrict__ W1, const float* __restrict__ b1,
    const float* __restrict__ W2, const float* __restrict__ b2,
    float* __restrict__ vn) {
    __shared__ float sW[128 * 128];
    __shared__ float sT[32 * 128];
    const int t = threadIdx.x;
    const int r0 = blockIdx.x * 32;
    {
        const float4* W4 = (const float4*)W1;
        float4* sW4 = (float4*)sW;
#pragma unroll
        for (int i = 0; i < 16; ++i) sW4[t + 256 * i] = W4[t + 256 * i];
    }
    __syncthreads();
    const int cg = t & 15;
    const int rp = t >> 4;
    const int ra = r0 + rp * 2, rb = ra + 1;
    const float inva = 1.f / fmaxf(counts[ra], 1.f);
    const float invb = 1.f / fmaxf(counts[rb], 1.f);

    float acc[2][8];
#pragma unroll
    for (int i = 0; i < 2; ++i)
#pragma unroll
        for (int j = 0; j < 8; ++j) acc[i][j] = 0.f;

    for (int k = 0; k < 128; ++k) {
        float a0 = vnacc[ra * 128 + k], a1 = vnacc[rb * 128 + k];
#pragma unroll
        for (int j2 = 0; j2 < 4; ++j2) {
            float2 wv = *(const float2*)&sW[k * 128 + cg * 2 + j2 * 32];
            acc[0][j2 * 2] += a0 * wv.x; acc[0][j2 * 2 + 1] += a0 * wv.y;
            acc[1][j2 * 2] += a1 * wv.x; acc[1][j2 * 2 + 1] += a1 * wv.y;
        }
    }
#pragma unroll
    for (int j2 = 0; j2 < 4; ++j2)
#pragma unroll
        for (int j1 = 0; j1 < 2; ++j1) {
            int c = cg * 2 + j1 + j2 * 32;
            float v0 = acc[0][j2 * 2 + j1] * inva + b1[c];
            v0 = v0 > 0.f ? v0 : 0.2f * v0;
            float v1 = acc[1][j2 * 2 + j1] * invb + b1[c];
            v1 = v1 > 0.f ? v1 : 0.2f * v1;
            sT[(rp * 2) * 128 + c] = v0;
            sT[(rp * 2 + 1) * 128 + c] = v1;
        }
    __syncthreads();
    {
        const float4* W4 = (const float4*)W2;
        float4* sW4 = (float4*)sW;
#pragma unroll
        for (int i = 0; i < 16; ++i) sW4[t + 256 * i] = W4[t + 256 * i];
    }
    __syncthreads();
    float acc2[2][8];
#pragma unroll
    for (int i = 0; i < 2; ++i)
#pragma unroll
        for (int j = 0; j < 8; ++j) acc2[i][j] = 0.f;
    for (int k = 0; k < 128; ++k) {
        float a0 = sT[(rp * 2) * 128 + k], a1 = sT[(rp * 2 + 1) * 128 + k];
#pragma unroll
        for (int j2 = 0; j2 < 4; ++j2) {
            float2 wv = *(const float2*)&sW[k * 128 + cg * 2 + j2 * 32];
            acc2[0][j2 * 2] += a0 * wv.x; acc2[0][j2 * 2 + 1] += a0 * wv.y;
            acc2[1][j2 * 2] += a1 * wv.x; acc2[1][j2 * 2 + 1] += a1 * wv.y;
        }
    }
#pragma unroll
    for (int j2 = 0; j2 < 4; ++j2)
#pragma unroll
        for (int j1 = 0; j1 < 2; ++j1) {
            int c = cg * 2 + j1 + j2 * 32;
            vn[ra * 128 + c] += acc2[0][j2 * 2 + j1] + b2[c];
            vn[rb * 128 + c] += acc2[1][j2 * 2 + j1] + b2[c];
        }
}

// ---------------- final ----------------
__global__ __launch_bounds__(256) void k_final(
    const float* __restrict__ pooled, const float* __restrict__ g,
    const float* __restrict__ b, const float* __restrict__ fcW,
    const float* __restrict__ fcb, float* __restrict__ out) {
    __shared__ float sP[4 * 128];
    const int t = threadIdx.x;
    for (int i = t; i < 512; i += 256) {
        int rr = i >> 7, c = i & 127;
        float v = pooled[(blockIdx.x * 4 + rr) * 128 + c];
        sP[i] = g[c] * v * BNS + b[c];
    }
    __syncthreads();
    const int brow = blockIdx.x * 4 + (t >> 6);
    const int o = t & 63;
    float acc = fcb[o];
    const float* wrow = fcW + o * 128;
    const float* prow = sP + (t >> 6) * 128;
    for (int k = 0; k < 128; ++k) acc += prow[k] * wrow[k];
    out[brow * 64 + o] = acc;
}

extern "C" void kernel_launch(void* const* d_in, const int* in_sizes, int n_in,
                              void* d_out, int out_size, void* d_ws, size_t ws_size,
                              hipStream_t stream) {
    const float* x       = (const float*)d_in[0];
    const int*   ei      = (const int*)d_in[1];
    const int*   batch   = (const int*)d_in[2];
    const float* node_W  = (const float*)d_in[3];
    const float* node_b  = (const float*)d_in[4];
    const float* conv_W1 = (const float*)d_in[5];
    const float* conv_b1 = (const float*)d_in[6];
    const float* conv_g  = (const float*)d_in[7];
    const float* conv_bt = (const float*)d_in[8];
    const float* conv_W2 = (const float*)d_in[9];
    const float* conv_b2 = (const float*)d_in[10];
    const float* vn_emb  = (const float*)d_in[11];
    const float* vn_W1   = (const float*)d_in[12];
    const float* vn_b1   = (const float*)d_in[13];
    const float* vn_W2   = (const float*)d_in[14];
    const float* vn_b2   = (const float*)d_in[15];
    const float* bn_g    = (const float*)d_in[16];
    const float* bn_b    = (const float*)d_in[17];
    const float* fc_W    = (const float*)d_in[18];
    const float* fc_b    = (const float*)d_in[19];
    float* out = (float*)d_out;

    float* ws = (float*)d_ws;
    float* h      = ws;                       // NN*128
    float* agg    = h + (size_t)NN * 128;     // NN*128
    float* vn     = agg + (size_t)NN * 128;   // NB*128
    float* vnacc  = vn + NB * 128;            // NB*128
    float* counts = vnacc + NB * 128;         // NB
    int* deg    = (int*)(counts + NB);        // NN
    int* off    = deg + NN;                   // NN+1
    int* cursor = off + NN + 1;               // NN
    int* csr    = cursor + NN;                // NE
    int* bstart = csr + NE;                   // NB+1
    int* part   = bstart + NB + 1;            // NSCB

    // ---- static structure: CSR by dst, batch ranges ----
    hipMemsetAsync(deg, 0, NN * sizeof(int), stream);
    k_deg<<<(NE + 255) / 256, 256, 0, stream>>>(ei, deg);
    k_scan1<<<NSCB, 256, 0, stream>>>(deg, part);
    k_scan2<<<1, 256, 0, stream>>>(part, off);
    k_scan3<<<NSCB, 256, 0, stream>>>(deg, part, off, cursor);
    k_fill<<<(NE + 255) / 256, 256, 0, stream>>>(ei, cursor, csr);
    k_bstart<<<3, 256, 0, stream>>>(batch, bstart);
    k_counts<<<2, 256, 0, stream>>>(bstart, counts);
    k_vn_init<<<(NB * 128) / 256, 256, 0, stream>>>(vn_emb, vn);

    // node encoder: h = x @ node_W + node_b
    k_gemm128<0><<<(NN + 127) / 128, 256, 0, stream>>>(
        x, node_W, node_b, nullptr, nullptr, h, NN);

    for (int l = 0; l < 3; ++l) {
        k_addvn<<<(NN * 32) / 256, 256, 0, stream>>>(h, vn, batch);
        // agg = h + sum of neighbor h (fuses the GIN self-add)
        k_gather<<<(NN + 7) / 8, 256, 0, stream>>>(off, csr, h, agg);
        // z = bn(leaky(agg @ W1 + b1))  (in-place agg)
        k_gemm128<2><<<(NN + 127) / 128, 256, 0, stream>>>(
            agg, conv_W1 + l * 16384, conv_b1 + l * 128,
            conv_g + l * 128, conv_bt + l * 128, agg, NN);
        // h = leaky(z @ W2 + b2)
        k_gemm128<1><<<(NN + 127) / 128, 256, 0, stream>>>(
            agg, conv_W2 + l * 16384, conv_b2 + l * 128,
            nullptr, nullptr, h, NN);
        k_pool2<<<NB, 256, 0, stream>>>(h, bstart, vnacc);
        k_vn_mlp<<<NB / 32, 256, 0, stream>>>(
            vnacc, counts, vn_W1 + l * 16384, vn_b1 + l * 128,
            vn_W2 + l * 16384, vn_b2 + l * 128, vn);
    }

    k_pool2<<<NB, 256, 0, stream>>>(h, bstart, vnacc);
    k_final<<<NB / 4, 256, 0, stream>>>(vnacc, bn_g, bn_b, fc_W, fc_b, out);
}

// Round 4
// 472.725 us; speedup vs baseline: 10.3133x; 1.3555x over previous
//
#include <hip/hip_runtime.h>
#include <hip/hip_bf16.h>

#define NN 50000
#define NE 800000
#define NB 512
#define NSCB 196   // scan blocks: 196*256 = 50176 >= NN
#define WT_S 136   // padded k-stride (bf16 elems) for transposed W
#define WT_M (128 * WT_S)  // elems per transposed weight matrix

using u32 = unsigned int;
using u16 = unsigned short;
typedef __attribute__((ext_vector_type(8))) short short8;
typedef __attribute__((ext_vector_type(4))) float f32x4;

constexpr float BNS = 0.9999950000374998f;  // 1/sqrt(1+1e-5)

__device__ inline u16 f2bf(float f) {
    u32 b = __builtin_bit_cast(u32, f);
    return (u16)((b + 0x7FFFu + ((b >> 16) & 1u)) >> 16);
}
__device__ inline float bf2f(u32 u) {
    return __builtin_bit_cast(float, u << 16);
}
__device__ inline u32 pk2(float a, float b) {
    return (u32)f2bf(a) | ((u32)f2bf(b) << 16);
}

// ---------------- weight prep: bf16 transpose+pad of 7 [128,128] matrices ----------------
// out[m][c][k] with k-stride WT_S;  m: 0=node_W, 1..3=conv_W1, 4..6=conv_W2
__global__ void k_wprep(const float* __restrict__ nW, const float* __restrict__ cW1,
                        const float* __restrict__ cW2, u16* __restrict__ wt) {
    int idx = blockIdx.x * 256 + threadIdx.x;  // < 7*16384
    int m = idx >> 14, e = idx & 16383;
    int k = e >> 7, c = e & 127;
    const float* src = m == 0 ? nW : (m <= 3 ? cW1 + (m - 1) * 16384 : cW2 + (m - 4) * 16384);
    wt[m * WT_M + c * WT_S + k] = f2bf(src[e]);
}

// ---------------- vn init ----------------
__global__ void k_vn_init(const float* __restrict__ vn_emb, float* __restrict__ vn) {
    int idx = blockIdx.x * 256 + threadIdx.x;  // < NB*128
    vn[idx] = vn_emb[idx & 127];
}

// ---------------- h += vn[batch]; also emit bf16 mirror ----------------
__global__ void k_addvn(float* __restrict__ h, u16* __restrict__ hb,
                        const float* __restrict__ vn, const int* __restrict__ batch) {
    int idx = blockIdx.x * 256 + threadIdx.x;  // < NN*32
    int i = idx >> 5, q = idx & 31;
    float4 v = ((float4*)h)[idx];
    float4 u = ((const float4*)vn)[batch[i] * 32 + q];
    v.x += u.x; v.y += u.y; v.z += u.z; v.w += u.w;
    ((float4*)h)[idx] = v;
    ((uint2*)hb)[idx] = make_uint2(pk2(v.x, v.y), pk2(v.z, v.w));
}

// ---------------- batch ranges (batch is sorted) ----------------
__global__ void k_bstart(const int* __restrict__ batch, int* __restrict__ bstart) {
    int b = blockIdx.x * 256 + threadIdx.x;
    if (b > NB) return;
    int lo = 0, hi = NN;
    while (lo < hi) { int m = (lo + hi) >> 1; if (batch[m] < b) lo = m + 1; else hi = m; }
    bstart[b] = lo;
}

__global__ void k_counts(const int* __restrict__ bstart, float* __restrict__ counts) {
    int b = blockIdx.x * 256 + threadIdx.x;
    if (b < NB) counts[b] = (float)(bstart[b + 1] - bstart[b]);
}

// ---------------- CSR build (by dst) ----------------
__global__ void k_deg(const int* __restrict__ ei, int* __restrict__ deg) {
    int e = blockIdx.x * 256 + threadIdx.x;
    if (e < NE) atomicAdd(&deg[ei[NE + e]], 1);
}

__global__ void k_scan1(const int* __restrict__ deg, int* __restrict__ part) {
    __shared__ int s[256];
    const int t = threadIdx.x;
    int i = blockIdx.x * 256 + t;
    s[t] = i < NN ? deg[i] : 0;
    __syncthreads();
    for (int d = 128; d > 0; d >>= 1) {
        if (t < d) s[t] += s[t + d];
        __syncthreads();
    }
    if (t == 0) part[blockIdx.x] = s[0];
}

__global__ void k_scan2(int* __restrict__ part, int* __restrict__ off) {
    __shared__ int s[256];
    const int t = threadIdx.x;
    s[t] = t < NSCB ? part[t] : 0;
    __syncthreads();
    for (int d = 1; d < 256; d <<= 1) {
        int v = (t >= d) ? s[t - d] : 0;
        __syncthreads();
        s[t] += v;
        __syncthreads();
    }
    if (t < NSCB) part[t] = t ? s[t - 1] : 0;
    if (t == NSCB - 1) off[NN] = s[t];
}

__global__ void k_scan3(const int* __restrict__ deg, const int* __restrict__ part,
                        int* __restrict__ off, int* __restrict__ cursor) {
    __shared__ int s[256];
    const int t = threadIdx.x;
    int i = blockIdx.x * 256 + t;
    int v = i < NN ? deg[i] : 0;
    s[t] = v;
    __syncthreads();
    for (int d = 1; d < 256; d <<= 1) {
        int u = (t >= d) ? s[t - d] : 0;
        __syncthreads();
        s[t] += u;
        __syncthreads();
    }
    if (i < NN) {
        int ex = part[blockIdx.x] + s[t] - v;
        off[i] = ex;
        cursor[i] = ex;
    }
}

__global__ void k_fill(const int* __restrict__ ei, int* __restrict__ cursor,
                       int* __restrict__ csr) {
    int e = blockIdx.x * 256 + threadIdx.x;
    if (e < NE) {
        int pos = atomicAdd(&cursor[ei[NE + e]], 1);
        csr[pos] = ei[e];
    }
}

// ---------------- gather (bf16): agg = h[d] + sum h[src]; hi/lo split out ----------------
__global__ __launch_bounds__(256) void k_gather(
    const int* __restrict__ off, const int* __restrict__ csr,
    const u16* __restrict__ hb, u16* __restrict__ ah, u16* __restrict__ alo) {
    int node = blockIdx.x * 8 + (threadIdx.x >> 5);
    int q = threadIdx.x & 31;
    if (node >= NN) return;
    const uint2* h2 = (const uint2*)hb;
    int s = off[node], e = off[node + 1];
    uint2 v = h2[(size_t)node * 32 + q];
    float4 A = {bf2f(v.x & 0xFFFFu), bf2f(v.x >> 16), bf2f(v.y & 0xFFFFu), bf2f(v.y >> 16)};
    float4 Bc = {0.f, 0.f, 0.f, 0.f};
    int j = s;
    for (; j + 1 < e; j += 2) {
        uint2 u0 = h2[(size_t)csr[j] * 32 + q];
        uint2 u1 = h2[(size_t)csr[j + 1] * 32 + q];
        A.x += bf2f(u0.x & 0xFFFFu); A.y += bf2f(u0.x >> 16);
        A.z += bf2f(u0.y & 0xFFFFu); A.w += bf2f(u0.y >> 16);
        Bc.x += bf2f(u1.x & 0xFFFFu); Bc.y += bf2f(u1.x >> 16);
        Bc.z += bf2f(u1.y & 0xFFFFu); Bc.w += bf2f(u1.y >> 16);
    }
    if (j < e) {
        uint2 u0 = h2[(size_t)csr[j] * 32 + q];
        A.x += bf2f(u0.x & 0xFFFFu); A.y += bf2f(u0.x >> 16);
        A.z += bf2f(u0.y & 0xFFFFu); A.w += bf2f(u0.y >> 16);
    }
    A.x += Bc.x; A.y += Bc.y; A.z += Bc.z; A.w += Bc.w;
    u16 h0 = f2bf(A.x), h1 = f2bf(A.y), h2_ = f2bf(A.z), h3 = f2bf(A.w);
    ((uint2*)ah)[(size_t)node * 32 + q] =
        make_uint2((u32)h0 | ((u32)h1 << 16), (u32)h2_ | ((u32)h3 << 16));
    ((uint2*)alo)[(size_t)node * 32 + q] =
        make_uint2(pk2(A.x - bf2f(h0), A.y - bf2f(h1)),
                   pk2(A.z - bf2f(h2_), A.w - bf2f(h3)));
}

// ---------------- MFMA GEMM: out = epi(A @ W + bias) ----------------
// A [nrows,128], Wt pre-transposed bf16 [col][k] stride WT_S, out [nrows,128]
// AMODE: 0 = bf16 A, 1 = bf16 hi+lo split (Ap,Ap2), 2 = f32 A split in-kernel
// EPI: 0 none, 1 leaky, 2 bn(leaky). OBF16: bf16 output.
template <int EPI, int AMODE, bool OBF16>
__global__ __launch_bounds__(256) void k_gemm(
    const void* __restrict__ Ap, const void* __restrict__ Ap2,
    const u16* __restrict__ wt, const float* __restrict__ bias,
    const float* __restrict__ gg, const float* __restrict__ bb,
    void* __restrict__ outp, int nrows) {
    __shared__ u16 sW[WT_M];
    const int t = threadIdx.x;
    {
        const float4* src = (const float4*)wt;
        float4* dst = (float4*)sW;
        for (int i = t; i < WT_M / 8; i += 256) dst[i] = src[i];
    }
    __syncthreads();
    const int lane = t & 63;
    const int w = t >> 6;
    const int rl = lane & 15;
    const int q = lane >> 4;
    const int rbase = blockIdx.x * 128 + w * 32;

    short8 af[2][4], al[2][4];
#pragma unroll
    for (int ri = 0; ri < 2; ++ri) {
        int row = min(rbase + ri * 16 + rl, nrows - 1);
#pragma unroll
        for (int kc = 0; kc < 4; ++kc) {
            if (AMODE == 2) {
                const float* ap = (const float*)Ap + (size_t)row * 128 + kc * 32 + q * 8;
                float4 f0 = *(const float4*)ap;
                float4 f1 = *(const float4*)(ap + 4);
                float fv[8] = {f0.x, f0.y, f0.z, f0.w, f1.x, f1.y, f1.z, f1.w};
                short8 hi, lo;
#pragma unroll
                for (int i = 0; i < 8; ++i) {
                    u16 hv = f2bf(fv[i]);
                    hi[i] = (short)hv;
                    lo[i] = (short)f2bf(fv[i] - bf2f(hv));
                }
                af[ri][kc] = hi;
                al[ri][kc] = lo;
            } else {
                af[ri][kc] = *(const short8*)((const u16*)Ap + (size_t)row * 128 + kc * 32 + q * 8);
                if (AMODE == 1)
                    al[ri][kc] = *(const short8*)((const u16*)Ap2 + (size_t)row * 128 + kc * 32 + q * 8);
            }
        }
    }

#pragma unroll
    for (int ct = 0; ct < 8; ++ct) {
        f32x4 acc0 = {0.f, 0.f, 0.f, 0.f};
        f32x4 acc1 = {0.f, 0.f, 0.f, 0.f};
#pragma unroll
        for (int kc = 0; kc < 4; ++kc) {
            short8 bf = *(const short8*)&sW[(ct * 16 + rl) * WT_S + kc * 32 + q * 8];
            if (AMODE != 0) {
                acc0 = __builtin_amdgcn_mfma_f32_16x16x32_bf16(al[0][kc], bf, acc0, 0, 0, 0);
                acc1 = __builtin_amdgcn_mfma_f32_16x16x32_bf16(al[1][kc], bf, acc1, 0, 0, 0);
            }
            acc0 = __builtin_amdgcn_mfma_f32_16x16x32_bf16(af[0][kc], bf, acc0, 0, 0, 0);
            acc1 = __builtin_amdgcn_mfma_f32_16x16x32_bf16(af[1][kc], bf, acc1, 0, 0, 0);
        }
        const int col = ct * 16 + rl;
        const float bs = bias[col];
        const float g = (EPI == 2) ? gg[col] : 0.f;
        const float be = (EPI == 2) ? bb[col] : 0.f;
#pragma unroll
        for (int i = 0; i < 4; ++i) {
            int r0 = rbase + q * 4 + i;
            if (r0 < nrows) {
                float v = acc0[i] + bs;
                if (EPI >= 1) v = v > 0.f ? v : 0.2f * v;
                if (EPI == 2) v = g * v * BNS + be;
                if (OBF16) ((u16*)outp)[(size_t)r0 * 128 + col] = f2bf(v);
                else ((float*)outp)[(size_t)r0 * 128 + col] = v;
            }
            int r1 = rbase + 16 + q * 4 + i;
            if (r1 < nrows) {
                float v = acc1[i] + bs;
                if (EPI >= 1) v = v > 0.f ? v : 0.2f * v;
                if (EPI == 2) v = g * v * BNS + be;
                if (OBF16) ((u16*)outp)[(size_t)r1 * 128 + col] = f2bf(v);
                else ((float*)outp)[(size_t)r1 * 128 + col] = v;
            }
        }
    }
}

// ---------------- segmented pool ----------------
__global__ __launch_bounds__(256) void k_pool2(
    const float* __restrict__ h, const int* __restrict__ bstart,
    float* __restrict__ acc) {
    const int b = blockIdx.x;
    const int s = bstart[b], e = bstart[b + 1];
    const int g = threadIdx.x >> 5;
    const int q = threadIdx.x & 31;
    const float4* h4 = (const float4*)h;
    float4 a = make_float4(0.f, 0.f, 0.f, 0.f);
    for (int r = s + g; r < e; r += 8) {
        float4 v = h4[(size_t)r * 32 + q];
        a.x += v.x; a.y += v.y; a.z += v.z; a.w += v.w;
    }
    __shared__ float4 red[8][32];
    red[g][q] = a;
    __syncthreads();
    if (g == 0) {
#pragma unroll
        for (int g2 = 1; g2 < 8; ++g2) {
            float4 v = red[g2][q];
            a.x += v.x; a.y += v.y; a.z += v.z; a.w += v.w;
        }
        ((float4*)acc)[b * 32 + q] = a;
    }
}

// ---------------- vn MLP ----------------
__global__ __launch_bounds__(256) void k_vn_mlp(
    const float* __restrict__ vnacc, const float* __restrict__ counts,
    const float* __restrict__ W1, const float* __restrict__ b1,
    const float* __restrict__ W2, const float* __restrict__ b2,
    float* __restrict__ vn) {
    __shared__ float sW[128 * 128];
    __shared__ float sT[32 * 128];
    const int t = threadIdx.x;
    const int r0 = blockIdx.x * 32;
    {
        const float4* W4 = (const float4*)W1;
        float4* sW4 = (float4*)sW;
#pragma unroll
        for (int i = 0; i < 16; ++i) sW4[t + 256 * i] = W4[t + 256 * i];
    }
    __syncthreads();
    const int cg = t & 15;
    const int rp = t >> 4;
    const int ra = r0 + rp * 2, rb = ra + 1;
    const float inva = 1.f / fmaxf(counts[ra], 1.f);
    const float invb = 1.f / fmaxf(counts[rb], 1.f);

    float acc[2][8];
#pragma unroll
    for (int i = 0; i < 2; ++i)
#pragma unroll
        for (int j = 0; j < 8; ++j) acc[i][j] = 0.f;

    for (int k = 0; k < 128; ++k) {
        float a0 = vnacc[ra * 128 + k], a1 = vnacc[rb * 128 + k];
#pragma unroll
        for (int j2 = 0; j2 < 4; ++j2) {
            float2 wv = *(const float2*)&sW[k * 128 + cg * 2 + j2 * 32];
            acc[0][j2 * 2] += a0 * wv.x; acc[0][j2 * 2 + 1] += a0 * wv.y;
            acc[1][j2 * 2] += a1 * wv.x; acc[1][j2 * 2 + 1] += a1 * wv.y;
        }
    }
#pragma unroll
    for (int j2 = 0; j2 < 4; ++j2)
#pragma unroll
        for (int j1 = 0; j1 < 2; ++j1) {
            int c = cg * 2 + j1 + j2 * 32;
            float v0 = acc[0][j2 * 2 + j1] * inva + b1[c];
            v0 = v0 > 0.f ? v0 : 0.2f * v0;
            float v1 = acc[1][j2 * 2 + j1] * invb + b1[c];
            v1 = v1 > 0.f ? v1 : 0.2f * v1;
            sT[(rp * 2) * 128 + c] = v0;
            sT[(rp * 2 + 1) * 128 + c] = v1;
        }
    __syncthreads();
    {
        const float4* W4 = (const float4*)W2;
        float4* sW4 = (float4*)sW;
#pragma unroll
        for (int i = 0; i < 16; ++i) sW4[t + 256 * i] = W4[t + 256 * i];
    }
    __syncthreads();
    float acc2[2][8];
#pragma unroll
    for (int i = 0; i < 2; ++i)
#pragma unroll
        for (int j = 0; j < 8; ++j) acc2[i][j] = 0.f;
    for (int k = 0; k < 128; ++k) {
        float a0 = sT[(rp * 2) * 128 + k], a1 = sT[(rp * 2 + 1) * 128 + k];
#pragma unroll
        for (int j2 = 0; j2 < 4; ++j2) {
            float2 wv = *(const float2*)&sW[k * 128 + cg * 2 + j2 * 32];
            acc2[0][j2 * 2] += a0 * wv.x; acc2[0][j2 * 2 + 1] += a0 * wv.y;
            acc2[1][j2 * 2] += a1 * wv.x; acc2[1][j2 * 2 + 1] += a1 * wv.y;
        }
    }
#pragma unroll
    for (int j2 = 0; j2 < 4; ++j2)
#pragma unroll
        for (int j1 = 0; j1 < 2; ++j1) {
            int c = cg * 2 + j1 + j2 * 32;
            vn[ra * 128 + c] += acc2[0][j2 * 2 + j1] + b2[c];
            vn[rb * 128 + c] += acc2[1][j2 * 2 + j1] + b2[c];
        }
}

// ---------------- final ----------------
__global__ __launch_bounds__(256) void k_final(
    const float* __restrict__ pooled, const float* __restrict__ g,
    const float* __restrict__ b, const float* __restrict__ fcW,
    const float* __restrict__ fcb, float* __restrict__ out) {
    __shared__ float sP[4 * 128];
    const int t = threadIdx.x;
    for (int i = t; i < 512; i += 256) {
        int rr = i >> 7, c = i & 127;
        float v = pooled[(blockIdx.x * 4 + rr) * 128 + c];
        sP[i] = g[c] * v * BNS + b[c];
    }
    __syncthreads();
    const int brow = blockIdx.x * 4 + (t >> 6);
    const int o = t & 63;
    float acc = fcb[o];
    const float* wrow = fcW + o * 128;
    const float* prow = sP + (t >> 6) * 128;
    for (int k = 0; k < 128; ++k) acc += prow[k] * wrow[k];
    out[brow * 64 + o] = acc;
}

extern "C" void kernel_launch(void* const* d_in, const int* in_sizes, int n_in,
                              void* d_out, int out_size, void* d_ws, size_t ws_size,
                              hipStream_t stream) {
    const float* x       = (const float*)d_in[0];
    const int*   ei      = (const int*)d_in[1];
    const int*   batch   = (const int*)d_in[2];
    const float* node_W  = (const float*)d_in[3];
    const float* node_b  = (const float*)d_in[4];
    const float* conv_W1 = (const float*)d_in[5];
    const float* conv_b1 = (const float*)d_in[6];
    const float* conv_g  = (const float*)d_in[7];
    const float* conv_bt = (const float*)d_in[8];
    const float* conv_W2 = (const float*)d_in[9];
    const float* conv_b2 = (const float*)d_in[10];
    const float* vn_emb  = (const float*)d_in[11];
    const float* vn_W1   = (const float*)d_in[12];
    const float* vn_b1   = (const float*)d_in[13];
    const float* vn_W2   = (const float*)d_in[14];
    const float* vn_b2   = (const float*)d_in[15];
    const float* bn_g    = (const float*)d_in[16];
    const float* bn_b    = (const float*)d_in[17];
    const float* fc_W    = (const float*)d_in[18];
    const float* fc_b    = (const float*)d_in[19];
    float* out = (float*)d_out;

    float* ws = (float*)d_ws;
    float* h    = ws;                            // NN*128 f32
    u16* hb     = (u16*)(h + (size_t)NN * 128);  // NN*128 bf16
    u16* aggh   = hb + (size_t)NN * 128;         // NN*128 bf16 (also z buffer)
    u16* agglo  = aggh + (size_t)NN * 128;       // NN*128 bf16
    u16* wt     = agglo + (size_t)NN * 128;      // 7*WT_M bf16
    float* vn     = (float*)(wt + 7 * WT_M);     // NB*128
    float* vnacc  = vn + NB * 128;               // NB*128
    float* counts = vnacc + NB * 128;            // NB
    int* deg    = (int*)(counts + NB);           // NN
    int* off    = deg + NN;                      // NN+1
    int* cursor = off + NN + 1;                  // NN
    int* csr    = cursor + NN;                   // NE
    int* bstart = csr + NE;                      // NB+1
    int* part   = bstart + NB + 1;               // NSCB

    // ---- static structure ----
    hipMemsetAsync(deg, 0, NN * sizeof(int), stream);
    k_wprep<<<448, 256, 0, stream>>>(node_W, conv_W1, conv_W2, wt);
    k_deg<<<(NE + 255) / 256, 256, 0, stream>>>(ei, deg);
    k_scan1<<<NSCB, 256, 0, stream>>>(deg, part);
    k_scan2<<<1, 256, 0, stream>>>(part, off);
    k_scan3<<<NSCB, 256, 0, stream>>>(deg, part, off, cursor);
    k_fill<<<(NE + 255) / 256, 256, 0, stream>>>(ei, cursor, csr);
    k_bstart<<<3, 256, 0, stream>>>(batch, bstart);
    k_counts<<<2, 256, 0, stream>>>(bstart, counts);
    k_vn_init<<<(NB * 128) / 256, 256, 0, stream>>>(vn_emb, vn);

    const int GG = (NN + 127) / 128;  // 391 gemm blocks

    // node encoder: h = x @ node_W + node_b  (f32 A, split in-kernel)
    k_gemm<0, 2, false><<<GG, 256, 0, stream>>>(
        x, nullptr, wt, node_b, nullptr, nullptr, h, NN);

    for (int l = 0; l < 3; ++l) {
        k_addvn<<<(NN * 32) / 256, 256, 0, stream>>>(h, hb, vn, batch);
        k_gather<<<(NN + 7) / 8, 256, 0, stream>>>(off, csr, hb, aggh, agglo);
        // z = bn(leaky(agg @ W1 + b1)) -> bf16, in-place into aggh
        k_gemm<2, 1, true><<<GG, 256, 0, stream>>>(
            aggh, agglo, wt + (size_t)(1 + l) * WT_M, conv_b1 + l * 128,
            conv_g + l * 128, conv_bt + l * 128, aggh, NN);
        // h = leaky(z @ W2 + b2) -> f32
        k_gemm<1, 0, false><<<GG, 256, 0, stream>>>(
            aggh, nullptr, wt + (size_t)(4 + l) * WT_M, conv_b2 + l * 128,
            nullptr, nullptr, h, NN);
        k_pool2<<<NB, 256, 0, stream>>>(h, bstart, vnacc);
        k_vn_mlp<<<NB / 32, 256, 0, stream>>>(
            vnacc, counts, vn_W1 + l * 16384, vn_b1 + l * 128,
            vn_W2 + l * 16384, vn_b2 + l * 128, vn);
    }

    k_pool2<<<NB, 256, 0, stream>>>(h, bstart, vnacc);
    k_final<<<NB / 4, 256, 0, stream>>>(vnacc, bn_g, bn_b, fc_W, fc_b, out);
}